// Round 11
// baseline (229.493 us; speedup 1.0000x reference)
//
#include <hip/hip_runtime.h>

typedef float f32x4 __attribute__((ext_vector_type(4)));
typedef short s16x8 __attribute__((ext_vector_type(8)));
typedef unsigned short u16x4 __attribute__((ext_vector_type(4)));
typedef unsigned short ushort_t;

__device__ __forceinline__ unsigned short f2bf(float f) {
    union { float f; unsigned int u; } v; v.f = f;
    unsigned int r = (v.u + 0x7fffu + ((v.u >> 16) & 1u)) >> 16;
    return (unsigned short)r;
}
__device__ __forceinline__ unsigned short tbf(float f) {  // truncate (f >= 0)
    union { float f; unsigned int u; } v; v.f = f;
    return (unsigned short)(v.u >> 16);
}
__device__ __forceinline__ float bf2f(unsigned short b) {
    union { unsigned int u; float f; } v; v.u = ((unsigned int)b) << 16;
    return v.f;
}

__device__ __forceinline__ f32x4 mfma_bf16(s16x8 a, s16x8 b, f32x4 c) {
    return __builtin_amdgcn_mfma_f32_16x16x32_bf16(a, b, c, 0, 0, 0);
}

__device__ __forceinline__ void gl_lds16(const void* g, void* l) {
    __builtin_amdgcn_global_load_lds(
        (const __attribute__((address_space(1))) unsigned int*)g,
        (__attribute__((address_space(3))) unsigned int*)l, 16, 0, 0);
}

// log2(e)/sqrt(512): fold exp->exp2 conversion into Q scale
#define QSCALE 0.06375871469f
// Fixed softmax offset (log2 domain) -- exact by shift-invariance; relu'd q,k
// keep scores in [0, ~16]; denominator >= 4096*2^-18 > 0.
#define FIXED_M 18.0f

// ---------------------------------------------------------------------------
// Kernel 1: QKV projection. y = relu(x @ W^T + b); q *= log2(e)/sqrt(512).
// q,k row-major [batch*4096][512]; v TRANSPOSED [batch][512][4096].
// ---------------------------------------------------------------------------
#define PLDK 40

__global__ __launch_bounds__(256) void qkv_proj(
    const float* __restrict__ x,
    const float* __restrict__ Wq, const float* __restrict__ bq,
    const float* __restrict__ Wk, const float* __restrict__ bk,
    const float* __restrict__ Wv, const float* __restrict__ bv,
    ushort_t* __restrict__ qkv_ws)
{
    const int mblk  = blockIdx.x;
    const int nblk  = blockIdx.y;
    const int which = blockIdx.z;

    const float* W    = (which == 0) ? Wq : (which == 1) ? Wk : Wv;
    const float* bias = (which == 0) ? bq : (which == 1) ? bk : bv;
    ushort_t* out = qkv_ws + (size_t)which * (8192u * 512u);
    const float scale = (which == 0) ? QSCALE : 1.0f;

    __shared__ ushort_t a_lds[128][PLDK];
    __shared__ ushort_t b_lds[128][PLDK];

    const int tid  = threadIdx.x;
    const int lane = tid & 63;
    const int wave = tid >> 6;
    const int wr = wave >> 1, wc = wave & 1;

    const int srow = tid >> 1;
    const int scol = (tid & 1) * 16;

    f32x4 acc[4][4] = {};

    for (int k0 = 0; k0 < 512; k0 += 32) {
        {
            const float* src = x + (size_t)(mblk * 128 + srow) * 512 + k0 + scol;
            ushort_t tmp[16];
            #pragma unroll
            for (int i = 0; i < 16; i++) tmp[i] = f2bf(src[i]);
            #pragma unroll
            for (int i = 0; i < 16; i++) a_lds[srow][scol + i] = tmp[i];
        }
        {
            const float* src = W + (size_t)(nblk * 128 + srow) * 512 + k0 + scol;
            ushort_t tmp[16];
            #pragma unroll
            for (int i = 0; i < 16; i++) tmp[i] = f2bf(src[i]);
            #pragma unroll
            for (int i = 0; i < 16; i++) b_lds[srow][scol + i] = tmp[i];
        }
        __syncthreads();

        s16x8 af[4], bf[4];
        #pragma unroll
        for (int m = 0; m < 4; m++)
            af[m] = *reinterpret_cast<const s16x8*>(&a_lds[wr * 64 + m * 16 + (lane & 15)][(lane >> 4) * 8]);
        #pragma unroll
        for (int n = 0; n < 4; n++)
            bf[n] = *reinterpret_cast<const s16x8*>(&b_lds[wc * 64 + n * 16 + (lane & 15)][(lane >> 4) * 8]);

        #pragma unroll
        for (int m = 0; m < 4; m++)
            #pragma unroll
            for (int n = 0; n < 4; n++)
                acc[m][n] = mfma_bf16(af[m], bf[n], acc[m][n]);

        __syncthreads();
    }

    if (which == 2) {
        #pragma unroll
        for (int n = 0; n < 4; n++) {
            const int col = nblk * 128 + wc * 64 + n * 16 + (lane & 15);
            const float b = bias[col];
            #pragma unroll
            for (int m = 0; m < 4; m++) {
                const int rowb = mblk * 128 + wr * 64 + m * 16 + (lane >> 4) * 4;
                const int batch = rowb >> 12, sr = rowb & 4095;
                u16x4 pk;
                #pragma unroll
                for (int j = 0; j < 4; j++)
                    pk[j] = f2bf(fmaxf(acc[m][n][j] + b, 0.0f));
                *reinterpret_cast<u16x4*>(out + (size_t)batch * 512 * 4096 +
                                          (size_t)col * 4096 + sr) = pk;
            }
        }
    } else {
        #pragma unroll
        for (int n = 0; n < 4; n++) {
            const int col = nblk * 128 + wc * 64 + n * 16 + (lane & 15);
            const float b = bias[col];
            #pragma unroll
            for (int m = 0; m < 4; m++) {
                #pragma unroll
                for (int j = 0; j < 4; j++) {
                    const int row = mblk * 128 + wr * 64 + m * 16 + (lane >> 4) * 4 + j;
                    float v = fmaxf(acc[m][n][j] + b, 0.0f) * scale;
                    out[(size_t)row * 512 + col] = f2bf(v);
                }
            }
        }
    }
}

// ---------------------------------------------------------------------------
// Kernel 2: flash attention, 64-row / 4-wave blocks, TWO blocks per CU
// (anti-phased on the LDS pipe). Wave w: QK for rows w*16..+15 (qf=64) +
// PV for cols w*128..+127 (O=128). Single-buffered K/V (69KB LDS),
// 4-barrier schedule with counted vmcnt(8). grid = (2*SP, 64) = 512 blocks.
// ---------------------------------------------------------------------------
__global__ __launch_bounds__(256, 2) void attn_v11(
    const ushort_t* __restrict__ qkv_ws,
    ushort_t* __restrict__ opart, float* __restrict__ ml,
    float* __restrict__ out, int SP, int NK)
{
    const int combo = blockIdx.x;
    const int batch = combo / SP;
    const int split = combo % SP;
    const int qblk  = blockIdx.y;
    const int tid = threadIdx.x, lane = tid & 63, w = tid >> 6;
    const int kv00 = split * (4096 / SP);

    const ushort_t* q_ws  = qkv_ws;
    const ushort_t* k_ws  = qkv_ws + (size_t)8192 * 512;
    const ushort_t* vt_ws = qkv_ws + (size_t)2 * 8192 * 512;  // [batch][512][4096]
    const size_t base  = (size_t)batch * 4096 * 512;
    const size_t vbase = (size_t)batch * 512 * 4096;

    __shared__ ushort_t k_lds[32 * 512];    // 32KB, XOR-swizzled 1KB rows
    __shared__ ushort_t vt_lds[512 * 32];   // 32KB, XOR-swizzled 64B rows
    __shared__ ushort_t p_lds[64][36];      // 4.6KB shared P
    __shared__ float l_lds[64];

    const int g = lane >> 4;
    const int l15 = lane & 15;

    // resident Q: wave w owns rows qblk*64 + w*16 .. +15 (64 VGPR)
    s16x8 qf[16];
    {
        const int qrow0 = qblk * 64 + w * 16 + l15;
        const ushort_t* qp = q_ws + base + (size_t)qrow0 * 512 + g * 8;
        #pragma unroll
        for (int ks = 0; ks < 16; ks++)
            qf[ks] = *reinterpret_cast<const s16x8*>(qp + ks * 32);
    }

    const f32x4 zf = {0.f, 0.f, 0.f, 0.f};
    f32x4 o[4][8];   // O[64 rows][128-col slice]: 4 row-frags x 8 col-frags
    #pragma unroll
    for (int rf = 0; rf < 4; rf++)
        #pragma unroll
        for (int cf = 0; cf < 8; cf++) o[rf][cf] = zf;
    float lrow[4] = {0.f, 0.f, 0.f, 0.f};

    // 8 gl_lds16 per thread per STAGE (32KB / 256 thr / 16B)
#define STAGE_K(KV0)                                                            \
    do {                                                                        \
        _Pragma("unroll")                                                       \
        for (int i = 0; i < 8; i++) {                                           \
            const int C   = i * 4096 + tid * 16;                                \
            const int row = C >> 10;                                            \
            const int Lc  = (C & 1023) ^ ((row & 7) << 4);                      \
            gl_lds16(k_ws + base + (size_t)((KV0) + row) * 512 + (Lc >> 1),     \
                     (char*)k_lds + C);                                         \
        }                                                                       \
    } while (0)
#define STAGE_V(KV0)                                                            \
    do {                                                                        \
        _Pragma("unroll")                                                       \
        for (int i = 0; i < 8; i++) {                                           \
            const int C    = i * 4096 + tid * 16;                               \
            const int drow = C >> 6;                                            \
            const int gc   = (C >> 4) & 3;                                      \
            const int gl   = gc ^ ((drow >> 1) & 3);                            \
            gl_lds16(vt_ws + vbase + (size_t)drow * 4096 + (KV0) + gl * 8,      \
                     (char*)vt_lds + C);                                        \
        }                                                                       \
    } while (0)

    // ---- prologue: K(0) awaited, V(0) in flight
    STAGE_K(kv00);
    STAGE_V(kv00);
    asm volatile("s_waitcnt vmcnt(8)" ::: "memory");
    __builtin_amdgcn_sched_barrier(0);
    __builtin_amdgcn_s_barrier();

    for (int t = 0; t < NK; ++t) {
        const int kv0 = kv00 + t * 32;

        // ---- QK^T : S[16 rows][32 keys] for this wave's rows
        f32x4 s0 = zf, s1 = zf;
        {
            const char* kb = (const char*)k_lds;
            #pragma unroll
            for (int ks = 0; ks < 16; ++ks) {
                const int xr = (ks * 64 + g * 16) ^ ((l15 & 7) << 4);
                const s16x8 kf0 = *reinterpret_cast<const s16x8*>(kb + l15 * 1024 + xr);
                const s16x8 kf1 = *reinterpret_cast<const s16x8*>(kb + (16 + l15) * 1024 + xr);
                s0 = mfma_bf16(qf[ks], kf0, s0);
                s1 = mfma_bf16(qf[ks], kf1, s1);
            }
        }

        // ---- P = exp2(S - FIXED_M) -> shared P; per-lane l partials
        #pragma unroll
        for (int j = 0; j < 4; j++) {
            const float p0 = exp2f(s0[j] - FIXED_M);
            const float p1 = exp2f(s1[j] - FIXED_M);
            lrow[j] += p0 + p1;
            const int pr = w * 16 + g * 4 + j;
            p_lds[pr][l15]      = tbf(p0);
            p_lds[pr][16 + l15] = tbf(p1);
        }

        // bar1: all QK reads of K-buf done + P complete
        asm volatile("s_waitcnt lgkmcnt(0)" ::: "memory");
        __builtin_amdgcn_sched_barrier(0);
        __builtin_amdgcn_s_barrier();

        // K-buf free: issue K(t+1). FIFO/wave: [V(t) 8, K(t+1) 8]
        if (t + 1 < NK) {
            STAGE_K(kv0 + 32);
            asm volatile("s_waitcnt vmcnt(8)" ::: "memory");  // V(t) landed
        } else {
            asm volatile("s_waitcnt vmcnt(0)" ::: "memory");
        }
        __builtin_amdgcn_sched_barrier(0);
        __builtin_amdgcn_s_barrier();   // bar2: everyone's V(t) landed

        // ---- PV (d-split): O[64 rows][wave's 128 cols] += P @ V-slice
        {
            const char* vb = (const char*)vt_lds;
            s16x8 pf[4];
            #pragma unroll
            for (int rf = 0; rf < 4; rf++)
                pf[rf] = *reinterpret_cast<const s16x8*>(&p_lds[rf * 16 + l15][g * 8]);
            #pragma unroll
            for (int cf = 0; cf < 8; cf++) {
                const int d = w * 128 + cf * 16 + l15;
                const s16x8 vf = *reinterpret_cast<const s16x8*>(
                    vb + d * 64 + ((g * 16) ^ (((d >> 1) & 3) << 4)));
                #pragma unroll
                for (int rf = 0; rf < 4; rf++)
                    o[rf][cf] = mfma_bf16(pf[rf], vf, o[rf][cf]);
            }
        }

        if (t + 1 < NK) {
            // bar3: all PV reads of V-buf (and P) done
            asm volatile("s_waitcnt lgkmcnt(0)" ::: "memory");
            __builtin_amdgcn_sched_barrier(0);
            __builtin_amdgcn_s_barrier();

            // V-buf free: issue V(t+1). FIFO/wave: [K(t+1) 8, V(t+1) 8]
            STAGE_V(kv0 + 32);
            asm volatile("s_waitcnt vmcnt(8)" ::: "memory");  // K(t+1) landed
            __builtin_amdgcn_sched_barrier(0);
            __builtin_amdgcn_s_barrier();   // bar4: everyone's K(t+1) landed
        }
    }
#undef STAGE_K
#undef STAGE_V

    // ---- l: reduce across 16 key-lanes
    #pragma unroll
    for (int j = 0; j < 4; j++) {
        #pragma unroll
        for (int msk = 8; msk >= 1; msk >>= 1)
            lrow[j] += __shfl_xor(lrow[j], msk, 64);
    }

    const int qrowb = qblk * 64;
    if (opart != nullptr) {
        const size_t prow8k = (size_t)batch * 4096;
        if (l15 == 0) {
            #pragma unroll
            for (int j = 0; j < 4; j++) {
                const size_t r = prow8k + qrowb + w * 16 + g * 4 + j;
                ml[((size_t)split * 8192 + r) * 2 + 1] = lrow[j];
            }
        }
        ushort_t* op = opart + (size_t)split * 8192 * 512;
        #pragma unroll
        for (int rf = 0; rf < 4; rf++) {
            #pragma unroll
            for (int cf = 0; cf < 8; cf++) {
                #pragma unroll
                for (int j = 0; j < 4; j++) {
                    const size_t r = prow8k + qrowb + rf * 16 + g * 4 + j;
                    op[r * 512 + w * 128 + cf * 16 + l15] = f2bf(o[rf][cf][j]);
                }
            }
        }
    } else {
        if (l15 == 0) {
            #pragma unroll
            for (int j = 0; j < 4; j++)
                l_lds[w * 16 + g * 4 + j] = lrow[j];
        }
        __builtin_amdgcn_s_barrier();
        #pragma unroll
        for (int rf = 0; rf < 4; rf++) {
            #pragma unroll
            for (int j = 0; j < 4; j++) {
                const int rl = rf * 16 + g * 4 + j;
                const float inv = 1.0f / l_lds[rl];
                #pragma unroll
                for (int cf = 0; cf < 8; cf++) {
                    out[base + (size_t)(qrowb + rl) * 512 + w * 128 + cf * 16 + l15]
                        = o[rf][cf][j] * inv;
                }
            }
        }
    }
}

// ---------------------------------------------------------------------------
// Kernel 3: merge KV-split partials. Fixed-M => equal weights:
// out = (sum_s O_s) / (sum_s l_s). 1 wave/row, 4 rows/block.
// ---------------------------------------------------------------------------
__global__ __launch_bounds__(256) void merge_kernel(
    const ushort_t* __restrict__ opart, const float* __restrict__ ml,
    float* __restrict__ out, int SP)
{
    const int row  = blockIdx.x * 4 + (threadIdx.x >> 6);
    const int lane = threadIdx.x & 63;

    float denom = 0.0f;
    for (int s = 0; s < SP; s++)
        denom += ml[((size_t)s * 8192 + row) * 2 + 1];
    const float inv = 1.0f / denom;

    float acc[8] = {};
    for (int s = 0; s < SP; s++) {
        const s16x8 v = *reinterpret_cast<const s16x8*>(
            opart + ((size_t)s * 8192 + row) * 512 + lane * 8);
        #pragma unroll
        for (int i = 0; i < 8; i++)
            acc[i] += bf2f((ushort_t)v[i]);
    }
    float* dst = out + (size_t)row * 512 + lane * 8;
    #pragma unroll
    for (int i = 0; i < 8; i++) dst[i] = acc[i] * inv;
}

extern "C" void kernel_launch(void* const* d_in, const int* in_sizes, int n_in,
                              void* d_out, int out_size, void* d_ws, size_t ws_size,
                              hipStream_t stream) {
    const float* x  = (const float*)d_in[0];
    const float* Wq = (const float*)d_in[1];
    const float* bq = (const float*)d_in[2];
    const float* Wk = (const float*)d_in[3];
    const float* bk = (const float*)d_in[4];
    const float* Wv = (const float*)d_in[5];
    const float* bv = (const float*)d_in[6];
    float* out = (float*)d_out;
    ushort_t* qkv = (ushort_t*)d_ws;  // q | k | vt, each 8192*512 bf16
    (void)in_sizes; (void)n_in; (void)out_size;

    const size_t qkv_bytes = 3ull * 8192 * 512 * 2;  // 25165824

    int SP = 0;
    if (ws_size >= qkv_bytes + 4ull * (8388608 + 65536)) SP = 4;
    else if (ws_size >= qkv_bytes + 2ull * (8388608 + 65536)) SP = 2;
    else if (ws_size >= qkv_bytes + 1ull * (8388608 + 65536)) SP = 1;

    dim3 gp(64, 4, 3);
    qkv_proj<<<gp, 256, 0, stream>>>(x, Wq, bq, Wk, bk, Wv, bv, qkv);

    if (SP > 0) {
        ushort_t* opart = qkv + 3ull * 8192 * 512;
        float* ml = (float*)(opart + (size_t)SP * 8192 * 512);
        dim3 ga(2 * SP, 64);
        attn_v11<<<ga, 256, 0, stream>>>(qkv, opart, ml, out, SP, (4096 / SP) / 32);
        merge_kernel<<<2048, 256, 0, stream>>>(opart, ml, out, SP);
    } else {
        dim3 ga(2, 64);
        attn_v11<<<ga, 256, 0, stream>>>(qkv, nullptr, nullptr, out, 1, 128);
    }
}

// Round 12
// 185.637 us; speedup vs baseline: 1.2362x; 1.2362x over previous
//
#include <hip/hip_runtime.h>

typedef float f32x4 __attribute__((ext_vector_type(4)));
typedef short s16x8 __attribute__((ext_vector_type(8)));
typedef unsigned short u16x4 __attribute__((ext_vector_type(4)));
typedef unsigned short ushort_t;

__device__ __forceinline__ unsigned short f2bf(float f) {
    union { float f; unsigned int u; } v; v.f = f;
    unsigned int r = (v.u + 0x7fffu + ((v.u >> 16) & 1u)) >> 16;
    return (unsigned short)r;
}
__device__ __forceinline__ unsigned short tbf(float f) {  // truncate (f >= 0)
    union { float f; unsigned int u; } v; v.f = f;
    return (unsigned short)(v.u >> 16);
}
__device__ __forceinline__ float bf2f(unsigned short b) {
    union { unsigned int u; float f; } v; v.u = ((unsigned int)b) << 16;
    return v.f;
}

__device__ __forceinline__ f32x4 mfma_bf16(s16x8 a, s16x8 b, f32x4 c) {
    return __builtin_amdgcn_mfma_f32_16x16x32_bf16(a, b, c, 0, 0, 0);
}

__device__ __forceinline__ void gl_lds16(const void* g, void* l) {
    __builtin_amdgcn_global_load_lds(
        (const __attribute__((address_space(1))) unsigned int*)g,
        (__attribute__((address_space(3))) unsigned int*)l, 16, 0, 0);
}

// log2(e)/sqrt(512): fold exp->exp2 conversion into Q scale
#define QSCALE 0.06375871469f
// Fixed softmax offset (log2 domain) -- exact by shift-invariance; relu'd q,k
// keep scores in [0, ~16]; denominator >= 4096*2^-18 > 0.
#define FIXED_M 18.0f

// ---------------------------------------------------------------------------
// Kernel 1: QKV projection. y = relu(x @ W^T + b); q *= log2(e)/sqrt(512).
// q,k row-major [batch*4096][512]; v TRANSPOSED [batch][512][4096].
// ---------------------------------------------------------------------------
#define PLDK 40

__global__ __launch_bounds__(256) void qkv_proj(
    const float* __restrict__ x,
    const float* __restrict__ Wq, const float* __restrict__ bq,
    const float* __restrict__ Wk, const float* __restrict__ bk,
    const float* __restrict__ Wv, const float* __restrict__ bv,
    ushort_t* __restrict__ qkv_ws)
{
    const int mblk  = blockIdx.x;
    const int nblk  = blockIdx.y;
    const int which = blockIdx.z;

    const float* W    = (which == 0) ? Wq : (which == 1) ? Wk : Wv;
    const float* bias = (which == 0) ? bq : (which == 1) ? bk : bv;
    ushort_t* out = qkv_ws + (size_t)which * (8192u * 512u);
    const float scale = (which == 0) ? QSCALE : 1.0f;

    __shared__ ushort_t a_lds[128][PLDK];
    __shared__ ushort_t b_lds[128][PLDK];

    const int tid  = threadIdx.x;
    const int lane = tid & 63;
    const int wave = tid >> 6;
    const int wr = wave >> 1, wc = wave & 1;

    const int srow = tid >> 1;
    const int scol = (tid & 1) * 16;

    f32x4 acc[4][4] = {};

    for (int k0 = 0; k0 < 512; k0 += 32) {
        {
            const float* src = x + (size_t)(mblk * 128 + srow) * 512 + k0 + scol;
            ushort_t tmp[16];
            #pragma unroll
            for (int i = 0; i < 16; i++) tmp[i] = f2bf(src[i]);
            #pragma unroll
            for (int i = 0; i < 16; i++) a_lds[srow][scol + i] = tmp[i];
        }
        {
            const float* src = W + (size_t)(nblk * 128 + srow) * 512 + k0 + scol;
            ushort_t tmp[16];
            #pragma unroll
            for (int i = 0; i < 16; i++) tmp[i] = f2bf(src[i]);
            #pragma unroll
            for (int i = 0; i < 16; i++) b_lds[srow][scol + i] = tmp[i];
        }
        __syncthreads();

        s16x8 af[4], bf[4];
        #pragma unroll
        for (int m = 0; m < 4; m++)
            af[m] = *reinterpret_cast<const s16x8*>(&a_lds[wr * 64 + m * 16 + (lane & 15)][(lane >> 4) * 8]);
        #pragma unroll
        for (int n = 0; n < 4; n++)
            bf[n] = *reinterpret_cast<const s16x8*>(&b_lds[wc * 64 + n * 16 + (lane & 15)][(lane >> 4) * 8]);

        #pragma unroll
        for (int m = 0; m < 4; m++)
            #pragma unroll
            for (int n = 0; n < 4; n++)
                acc[m][n] = mfma_bf16(af[m], bf[n], acc[m][n]);

        __syncthreads();
    }

    if (which == 2) {
        #pragma unroll
        for (int n = 0; n < 4; n++) {
            const int col = nblk * 128 + wc * 64 + n * 16 + (lane & 15);
            const float b = bias[col];
            #pragma unroll
            for (int m = 0; m < 4; m++) {
                const int rowb = mblk * 128 + wr * 64 + m * 16 + (lane >> 4) * 4;
                const int batch = rowb >> 12, sr = rowb & 4095;
                u16x4 pk;
                #pragma unroll
                for (int j = 0; j < 4; j++)
                    pk[j] = f2bf(fmaxf(acc[m][n][j] + b, 0.0f));
                *reinterpret_cast<u16x4*>(out + (size_t)batch * 512 * 4096 +
                                          (size_t)col * 4096 + sr) = pk;
            }
        }
    } else {
        #pragma unroll
        for (int n = 0; n < 4; n++) {
            const int col = nblk * 128 + wc * 64 + n * 16 + (lane & 15);
            const float b = bias[col];
            #pragma unroll
            for (int m = 0; m < 4; m++) {
                #pragma unroll
                for (int j = 0; j < 4; j++) {
                    const int row = mblk * 128 + wr * 64 + m * 16 + (lane >> 4) * 4 + j;
                    float v = fmaxf(acc[m][n][j] + b, 0.0f) * scale;
                    out[(size_t)row * 512 + col] = f2bf(v);
                }
            }
        }
    }
}

// ---------------------------------------------------------------------------
// Kernel 2: flash attention, D-SPLIT PV (v10 architecture) + counted vmcnt.
// 8 waves x 512 thr, 128 q-rows/block. QK: wave w owns 16 q-rows (qf=64).
// PV: wave w owns a 64-wide d-slice of O for ALL 128 rows (O=128 AGPR).
// ~200 regs/wave -> 2 waves/SIMD. Per-wave load FIFO: [V(t)4, K(t+1)4,
// V(t+1)4]; bar1 waits vmcnt(8) (V(t) landed), bar2 waits vmcnt(4)
// (K(t+1) landed) -- V(t+1) stays in flight across both barriers.
// grid = (2*SP, 32).
// ---------------------------------------------------------------------------
__global__ __launch_bounds__(512, 2) void attn_v12(
    const ushort_t* __restrict__ qkv_ws,
    ushort_t* __restrict__ opart, float* __restrict__ ml,
    float* __restrict__ out, int SP, int NK)
{
    const int combo = blockIdx.x;
    const int batch = combo / SP;
    const int split = combo % SP;
    const int qblk  = blockIdx.y;
    const int tid = threadIdx.x, lane = tid & 63, wave = tid >> 6;
    const int kv00 = split * (4096 / SP);

    const ushort_t* q_ws  = qkv_ws;
    const ushort_t* k_ws  = qkv_ws + (size_t)8192 * 512;
    const ushort_t* vt_ws = qkv_ws + (size_t)2 * 8192 * 512;  // [batch][512][4096]
    const size_t base  = (size_t)batch * 4096 * 512;
    const size_t vbase = (size_t)batch * 512 * 4096;

    __shared__ ushort_t k_lds[2][32 * 512];    // 64KB, XOR-swizzled 1KB rows
    __shared__ ushort_t vt_lds[2][512 * 32];   // 64KB, XOR-swizzled 64B rows
    __shared__ ushort_t p_lds[128][40];        // 10KB shared P (pad 40: 80B rows)
    __shared__ float l_lds[128];

    const int g = lane >> 4;
    const int l15 = lane & 15;

    // resident Q: 16 rows/wave, 16 k-steps (64 VGPR)
    s16x8 qf[16];
    {
        const int qrow0 = qblk * 128 + wave * 16 + l15;
        const ushort_t* qp = q_ws + base + (size_t)qrow0 * 512 + g * 8;
        #pragma unroll
        for (int ks = 0; ks < 16; ks++)
            qf[ks] = *reinterpret_cast<const s16x8*>(qp + ks * 32);
    }

    const f32x4 zf = {0.f, 0.f, 0.f, 0.f};
    f32x4 o[8][4];   // O[128 rows][64-col slice]: 8 row-frags x 4 col-frags
    #pragma unroll
    for (int rf = 0; rf < 8; rf++)
        #pragma unroll
        for (int cf = 0; cf < 4; cf++) o[rf][cf] = zf;
    float lrow[4] = {0.f, 0.f, 0.f, 0.f};

    // K loads first, V loads second (FIFO order matters for counted vmcnt)
#define STAGE(BUF, KV0)                                                         \
    do {                                                                        \
        _Pragma("unroll")                                                       \
        for (int i = 0; i < 4; i++) {                                           \
            const int C   = i * 8192 + tid * 16;                                \
            const int row = C >> 10;                                            \
            const int Lc  = (C & 1023) ^ ((row & 7) << 4);                      \
            gl_lds16(k_ws + base + (size_t)((KV0) + row) * 512 + (Lc >> 1),     \
                     (char*)&k_lds[BUF][0] + C);                                \
        }                                                                       \
        _Pragma("unroll")                                                       \
        for (int i = 0; i < 4; i++) {                                           \
            const int C    = i * 8192 + tid * 16;                               \
            const int drow = C >> 6;                                            \
            const int gc   = (C >> 4) & 3;                                      \
            const int gl   = gc ^ ((drow >> 1) & 3);                            \
            gl_lds16(vt_ws + vbase + (size_t)drow * 4096 + (KV0) + gl * 8,      \
                     (char*)&vt_lds[BUF][0] + C);                               \
        }                                                                       \
    } while (0)

    // prologue: K0 awaited (V0 stays in flight)
    STAGE(0, kv00);
    asm volatile("s_waitcnt vmcnt(4)" ::: "memory");
    __builtin_amdgcn_sched_barrier(0);
    __builtin_amdgcn_s_barrier();

    int cur = 0;
    for (int t = 0; t < NK; ++t) {
        if (t + 1 < NK) STAGE(cur ^ 1, kv00 + (t + 1) * 32);
        // FIFO now: [V(t) 4, K(t+1) 4, V(t+1) 4]

        // ---- QK^T : S[16 rows][32 keys] for this wave's rows
        const char* kb = (const char*)&k_lds[cur][0];
        f32x4 s0 = zf, s1 = zf;
        #pragma unroll
        for (int ks = 0; ks < 16; ++ks) {
            const int xr = (ks * 64 + g * 16) ^ ((l15 & 7) << 4);
            const s16x8 kf0 = *reinterpret_cast<const s16x8*>(kb + l15 * 1024 + xr);
            const s16x8 kf1 = *reinterpret_cast<const s16x8*>(kb + (16 + l15) * 1024 + xr);
            s0 = mfma_bf16(qf[ks], kf0, s0);
            s1 = mfma_bf16(qf[ks], kf1, s1);
        }

        // ---- P = exp2(S - FIXED_M) -> shared P LDS; per-lane l partials
        #pragma unroll
        for (int j = 0; j < 4; j++) {
            const float p0 = exp2f(s0[j] - FIXED_M);
            const float p1 = exp2f(s1[j] - FIXED_M);
            lrow[j] += p0 + p1;
            const int pr = wave * 16 + g * 4 + j;
            p_lds[pr][l15]      = tbf(p0);
            p_lds[pr][16 + l15] = tbf(p1);
        }

        // bar1: P visible + QK reads done + V(t) landed (K/V(t+1) in flight)
        if (t + 1 < NK)
            asm volatile("s_waitcnt vmcnt(8) lgkmcnt(0)" ::: "memory");
        else
            asm volatile("s_waitcnt vmcnt(0) lgkmcnt(0)" ::: "memory");
        __builtin_amdgcn_sched_barrier(0);
        __builtin_amdgcn_s_barrier();
        __builtin_amdgcn_sched_barrier(0);

        // ---- PV (d-split): O[128 rows][wave's 64 cols] += P[128][32] @ V-slice
        {
            const char* vb = (const char*)&vt_lds[cur][0];
            s16x8 vf[4];
            #pragma unroll
            for (int cf = 0; cf < 4; cf++) {
                const int d = wave * 64 + cf * 16 + l15;
                vf[cf] = *reinterpret_cast<const s16x8*>(
                    vb + d * 64 + ((g * 16) ^ (((d >> 1) & 3) << 4)));
            }
            #pragma unroll
            for (int rf = 0; rf < 8; rf++) {
                const s16x8 pf = *reinterpret_cast<const s16x8*>(
                    &p_lds[rf * 16 + l15][g * 8]);
                #pragma unroll
                for (int cf = 0; cf < 4; cf++)
                    o[rf][cf] = mfma_bf16(pf, vf[cf], o[rf][cf]);
            }
        }

        // bar2: PV reads done (v-buf & P free) + K(t+1) landed
        //       (V(t+1)'s 4 loads stay in flight through next QK)
        if (t + 1 < NK)
            asm volatile("s_waitcnt vmcnt(4) lgkmcnt(0)" ::: "memory");
        else
            asm volatile("s_waitcnt vmcnt(0) lgkmcnt(0)" ::: "memory");
        __builtin_amdgcn_sched_barrier(0);
        __builtin_amdgcn_s_barrier();
        __builtin_amdgcn_sched_barrier(0);
        cur ^= 1;
    }
#undef STAGE

    // ---- l: reduce across 16 key-lanes; publish per-row
    #pragma unroll
    for (int j = 0; j < 4; j++) {
        #pragma unroll
        for (int msk = 8; msk >= 1; msk >>= 1)
            lrow[j] += __shfl_xor(lrow[j], msk, 64);
    }
    if (l15 == 0) {
        #pragma unroll
        for (int j = 0; j < 4; j++)
            l_lds[wave * 16 + g * 4 + j] = lrow[j];
    }
    __builtin_amdgcn_s_barrier();

    const int qrowb = qblk * 128;
    if (opart != nullptr) {
        const size_t prow8k = (size_t)batch * 4096;
        if (l15 == 0) {
            #pragma unroll
            for (int j = 0; j < 4; j++) {
                const size_t r = prow8k + qrowb + wave * 16 + g * 4 + j;
                ml[((size_t)split * 8192 + r) * 2 + 1] = lrow[j];
            }
        }
        ushort_t* op = opart + (size_t)split * 8192 * 512;
        #pragma unroll
        for (int rf = 0; rf < 8; rf++) {
            #pragma unroll
            for (int cf = 0; cf < 4; cf++) {
                #pragma unroll
                for (int j = 0; j < 4; j++) {
                    const size_t r = prow8k + qrowb + rf * 16 + g * 4 + j;
                    op[r * 512 + wave * 64 + cf * 16 + l15] = f2bf(o[rf][cf][j]);
                }
            }
        }
    } else {
        #pragma unroll
        for (int rf = 0; rf < 8; rf++) {
            #pragma unroll
            for (int j = 0; j < 4; j++) {
                const int rl = rf * 16 + g * 4 + j;
                const float inv = 1.0f / l_lds[rl];
                #pragma unroll
                for (int cf = 0; cf < 4; cf++) {
                    out[base + (size_t)(qrowb + rl) * 512 + wave * 64 + cf * 16 + l15]
                        = o[rf][cf][j] * inv;
                }
            }
        }
    }
}

// ---------------------------------------------------------------------------
// Kernel 3: merge KV-split partials. Fixed-M => equal weights:
// out = (sum_s O_s) / (sum_s l_s). 1 wave/row, 4 rows/block.
// ---------------------------------------------------------------------------
__global__ __launch_bounds__(256) void merge_kernel(
    const ushort_t* __restrict__ opart, const float* __restrict__ ml,
    float* __restrict__ out, int SP)
{
    const int row  = blockIdx.x * 4 + (threadIdx.x >> 6);
    const int lane = threadIdx.x & 63;

    float denom = 0.0f;
    for (int s = 0; s < SP; s++)
        denom += ml[((size_t)s * 8192 + row) * 2 + 1];
    const float inv = 1.0f / denom;

    float acc[8] = {};
    for (int s = 0; s < SP; s++) {
        const s16x8 v = *reinterpret_cast<const s16x8*>(
            opart + ((size_t)s * 8192 + row) * 512 + lane * 8);
        #pragma unroll
        for (int i = 0; i < 8; i++)
            acc[i] += bf2f((ushort_t)v[i]);
    }
    float* dst = out + (size_t)row * 512 + lane * 8;
    #pragma unroll
    for (int i = 0; i < 8; i++) dst[i] = acc[i] * inv;
}

extern "C" void kernel_launch(void* const* d_in, const int* in_sizes, int n_in,
                              void* d_out, int out_size, void* d_ws, size_t ws_size,
                              hipStream_t stream) {
    const float* x  = (const float*)d_in[0];
    const float* Wq = (const float*)d_in[1];
    const float* bq = (const float*)d_in[2];
    const float* Wk = (const float*)d_in[3];
    const float* bk = (const float*)d_in[4];
    const float* Wv = (const float*)d_in[5];
    const float* bv = (const float*)d_in[6];
    float* out = (float*)d_out;
    ushort_t* qkv = (ushort_t*)d_ws;  // q | k | vt, each 8192*512 bf16
    (void)in_sizes; (void)n_in; (void)out_size;

    const size_t qkv_bytes = 3ull * 8192 * 512 * 2;  // 25165824

    int SP = 0;
    if (ws_size >= qkv_bytes + 4ull * (8388608 + 65536)) SP = 4;
    else if (ws_size >= qkv_bytes + 2ull * (8388608 + 65536)) SP = 2;
    else if (ws_size >= qkv_bytes + 1ull * (8388608 + 65536)) SP = 1;

    dim3 gp(64, 4, 3);
    qkv_proj<<<gp, 256, 0, stream>>>(x, Wq, bq, Wk, bk, Wv, bv, qkv);

    if (SP > 0) {
        ushort_t* opart = qkv + 3ull * 8192 * 512;
        float* ml = (float*)(opart + (size_t)SP * 8192 * 512);
        dim3 ga(2 * SP, 32);
        attn_v12<<<ga, 512, 0, stream>>>(qkv, opart, ml, out, SP, (4096 / SP) / 32);
        merge_kernel<<<2048, 256, 0, stream>>>(opart, ml, out, SP);
    } else {
        dim3 ga(2, 32);
        attn_v12<<<ga, 512, 0, stream>>>(qkv, nullptr, nullptr, out, 1, 128);
    }
}

// Round 13
// 150.498 us; speedup vs baseline: 1.5249x; 1.2335x over previous
//
#include <hip/hip_runtime.h>

typedef float f32x4 __attribute__((ext_vector_type(4)));
typedef short s16x8 __attribute__((ext_vector_type(8)));
typedef unsigned short u16x4 __attribute__((ext_vector_type(4)));
typedef unsigned short ushort_t;

__device__ __forceinline__ unsigned short f2bf(float f) {
    union { float f; unsigned int u; } v; v.f = f;
    unsigned int r = (v.u + 0x7fffu + ((v.u >> 16) & 1u)) >> 16;
    return (unsigned short)r;
}
__device__ __forceinline__ unsigned short tbf(float f) {  // truncate (f >= 0)
    union { float f; unsigned int u; } v; v.f = f;
    return (unsigned short)(v.u >> 16);
}
__device__ __forceinline__ float bf2f(unsigned short b) {
    union { unsigned int u; float f; } v; v.u = ((unsigned int)b) << 16;
    return v.f;
}

__device__ __forceinline__ f32x4 mfma_bf16(s16x8 a, s16x8 b, f32x4 c) {
    return __builtin_amdgcn_mfma_f32_16x16x32_bf16(a, b, c, 0, 0, 0);
}

__device__ __forceinline__ void gl_lds16(const void* g, void* l) {
    __builtin_amdgcn_global_load_lds(
        (const __attribute__((address_space(1))) unsigned int*)g,
        (__attribute__((address_space(3))) unsigned int*)l, 16, 0, 0);
}

// log2(e)/sqrt(512): fold exp->exp2 conversion into Q scale
#define QSCALE 0.06375871469f
// Fixed softmax offset (log2 domain) -- exact by shift-invariance; relu'd q,k
// keep scores in [0, ~16]; denominator >= 4096*2^-18 > 0.
#define FIXED_M 18.0f

// ---------------------------------------------------------------------------
// Kernel 1: FUSED QKV projection. One block computes Q, K, V tiles for its
// (m,n): x staged+converted ONCE (was 3x), float4 loads + packed u16x4
// stores. q,k row-major [batch*4096][512] (q *= QSCALE); v TRANSPOSED
// [batch][512][4096]. grid = (64, 4), 256 thr, 4 waves 2x2.
// ---------------------------------------------------------------------------
__global__ __launch_bounds__(256) void qkv_proj_fused(
    const float* __restrict__ x,
    const float* __restrict__ Wq, const float* __restrict__ bq,
    const float* __restrict__ Wk, const float* __restrict__ bk,
    const float* __restrict__ Wv, const float* __restrict__ bv,
    ushort_t* __restrict__ qkv_ws)
{
    const int mblk = blockIdx.x;
    const int nblk = blockIdx.y;

    __shared__ ushort_t a_lds[128][40];
    __shared__ ushort_t b_lds[3][128][40];

    const int tid  = threadIdx.x;
    const int lane = tid & 63;
    const int wave = tid >> 6;
    const int wr = wave >> 1, wc = wave & 1;

    f32x4 acc[3][4][4] = {};

    for (int k0 = 0; k0 < 512; k0 += 32) {
        // stage A (x) once: 128x32 fp32 -> bf16, float4 loads, u16x4 stores
        #pragma unroll
        for (int i = 0; i < 4; i++) {
            const int chunk = i * 256 + tid;           // 0..1023
            const int row = chunk >> 3, c4 = (chunk & 7) * 4;
            const float4 v = *reinterpret_cast<const float4*>(
                x + (size_t)(mblk * 128 + row) * 512 + k0 + c4);
            u16x4 pk;
            pk[0] = f2bf(v.x); pk[1] = f2bf(v.y);
            pk[2] = f2bf(v.z); pk[3] = f2bf(v.w);
            *reinterpret_cast<u16x4*>(&a_lds[row][c4]) = pk;
        }
        // stage B x3 (Wq, Wk, Wv)
        #pragma unroll
        for (int wsel = 0; wsel < 3; wsel++) {
            const float* W = (wsel == 0) ? Wq : (wsel == 1) ? Wk : Wv;
            #pragma unroll
            for (int i = 0; i < 4; i++) {
                const int chunk = i * 256 + tid;
                const int row = chunk >> 3, c4 = (chunk & 7) * 4;
                const float4 v = *reinterpret_cast<const float4*>(
                    W + (size_t)(nblk * 128 + row) * 512 + k0 + c4);
                u16x4 pk;
                pk[0] = f2bf(v.x); pk[1] = f2bf(v.y);
                pk[2] = f2bf(v.z); pk[3] = f2bf(v.w);
                *reinterpret_cast<u16x4*>(&b_lds[wsel][row][c4]) = pk;
            }
        }
        __syncthreads();

        s16x8 af[4];
        #pragma unroll
        for (int m = 0; m < 4; m++)
            af[m] = *reinterpret_cast<const s16x8*>(
                &a_lds[wr * 64 + m * 16 + (lane & 15)][(lane >> 4) * 8]);
        #pragma unroll
        for (int wsel = 0; wsel < 3; wsel++) {
            s16x8 bf[4];
            #pragma unroll
            for (int n = 0; n < 4; n++)
                bf[n] = *reinterpret_cast<const s16x8*>(
                    &b_lds[wsel][wc * 64 + n * 16 + (lane & 15)][(lane >> 4) * 8]);
            #pragma unroll
            for (int m = 0; m < 4; m++)
                #pragma unroll
                for (int n = 0; n < 4; n++)
                    acc[wsel][m][n] = mfma_bf16(af[m], bf[n], acc[wsel][m][n]);
        }
        __syncthreads();
    }

    // ---- epilogues: Q (scaled, row-major), K (row-major), V (transposed)
    #pragma unroll
    for (int wsel = 0; wsel < 3; wsel++) {
        const float* bias = (wsel == 0) ? bq : (wsel == 1) ? bk : bv;
        ushort_t* out = qkv_ws + (size_t)wsel * (8192u * 512u);
        const float scale = (wsel == 0) ? QSCALE : 1.0f;
        if (wsel == 2) {
            #pragma unroll
            for (int n = 0; n < 4; n++) {
                const int col = nblk * 128 + wc * 64 + n * 16 + (lane & 15);
                const float b = bias[col];
                #pragma unroll
                for (int m = 0; m < 4; m++) {
                    const int rowb = mblk * 128 + wr * 64 + m * 16 + (lane >> 4) * 4;
                    const int batch = rowb >> 12, sr = rowb & 4095;
                    u16x4 pk;
                    #pragma unroll
                    for (int j = 0; j < 4; j++)
                        pk[j] = f2bf(fmaxf(acc[2][m][n][j] + b, 0.0f));
                    *reinterpret_cast<u16x4*>(out + (size_t)batch * 512 * 4096 +
                                              (size_t)col * 4096 + sr) = pk;
                }
            }
        } else {
            #pragma unroll
            for (int n = 0; n < 4; n++) {
                const int col = nblk * 128 + wc * 64 + n * 16 + (lane & 15);
                const float b = bias[col];
                #pragma unroll
                for (int m = 0; m < 4; m++) {
                    #pragma unroll
                    for (int j = 0; j < 4; j++) {
                        const int row = mblk * 128 + wr * 64 + m * 16 + (lane >> 4) * 4 + j;
                        float v = fmaxf(acc[wsel][m][n][j] + b, 0.0f) * scale;
                        out[(size_t)row * 512 + col] = f2bf(v);
                    }
                }
            }
        }
    }
}

// ---------------------------------------------------------------------------
// Kernel 2: flash attention, D-SPLIT PV (v10, proven 109us — restored
// verbatim). 8 waves x 512 thr, 128 q-rows/block. QK: wave owns 16 q-rows
// (qf=64). PV: wave owns a 64-wide d-slice of O for ALL 128 rows (O=128
// AGPR). 2 waves/SIMD. grid = (2*SP, 32).
// ---------------------------------------------------------------------------
__global__ __launch_bounds__(512, 2) void attn_v10(
    const ushort_t* __restrict__ qkv_ws,
    ushort_t* __restrict__ opart, float* __restrict__ ml,
    float* __restrict__ out, int SP, int NK)
{
    const int combo = blockIdx.x;
    const int batch = combo / SP;
    const int split = combo % SP;
    const int qblk  = blockIdx.y;
    const int tid = threadIdx.x, lane = tid & 63, wave = tid >> 6;
    const int kv00 = split * (4096 / SP);

    const ushort_t* q_ws  = qkv_ws;
    const ushort_t* k_ws  = qkv_ws + (size_t)8192 * 512;
    const ushort_t* vt_ws = qkv_ws + (size_t)2 * 8192 * 512;  // [batch][512][4096]
    const size_t base  = (size_t)batch * 4096 * 512;
    const size_t vbase = (size_t)batch * 512 * 4096;

    __shared__ ushort_t k_lds[2][32 * 512];    // 64KB, XOR-swizzled 1KB rows
    __shared__ ushort_t vt_lds[2][512 * 32];   // 64KB, XOR-swizzled 64B rows
    __shared__ ushort_t p_lds[128][36];        // 9KB shared P (pad 36)
    __shared__ float l_lds[128];

    const int g = lane >> 4;
    const int l15 = lane & 15;

    // resident Q: 16 rows/wave, 16 k-steps (64 VGPR)
    s16x8 qf[16];
    {
        const int qrow0 = qblk * 128 + wave * 16 + l15;
        const ushort_t* qp = q_ws + base + (size_t)qrow0 * 512 + g * 8;
        #pragma unroll
        for (int ks = 0; ks < 16; ks++)
            qf[ks] = *reinterpret_cast<const s16x8*>(qp + ks * 32);
    }

    const f32x4 zf = {0.f, 0.f, 0.f, 0.f};
    f32x4 o[8][4];   // O[128 rows][64-col slice]: 8 row-frags x 4 col-frags
    #pragma unroll
    for (int rf = 0; rf < 8; rf++)
        #pragma unroll
        for (int cf = 0; cf < 4; cf++) o[rf][cf] = zf;
    float lrow[4] = {0.f, 0.f, 0.f, 0.f};

#define STAGE(BUF, KV0)                                                         \
    do {                                                                        \
        _Pragma("unroll")                                                       \
        for (int i = 0; i < 4; i++) {                                           \
            const int C   = i * 8192 + tid * 16;                                \
            const int row = C >> 10;                                            \
            const int Lc  = (C & 1023) ^ ((row & 7) << 4);                      \
            gl_lds16(k_ws + base + (size_t)((KV0) + row) * 512 + (Lc >> 1),     \
                     (char*)&k_lds[BUF][0] + C);                                \
        }                                                                       \
        _Pragma("unroll")                                                       \
        for (int i = 0; i < 4; i++) {                                           \
            const int C    = i * 8192 + tid * 16;                               \
            const int drow = C >> 6;                                            \
            const int gc   = (C >> 4) & 3;                                      \
            const int gl   = gc ^ ((drow >> 1) & 3);                            \
            gl_lds16(vt_ws + vbase + (size_t)drow * 4096 + (KV0) + gl * 8,      \
                     (char*)&vt_lds[BUF][0] + C);                               \
        }                                                                       \
    } while (0)

    // prologue
    STAGE(0, kv00);
    asm volatile("s_waitcnt vmcnt(0)" ::: "memory");
    __builtin_amdgcn_s_barrier();

    int cur = 0;
    for (int t = 0; t < NK; ++t) {
        if (t + 1 < NK) STAGE(cur ^ 1, kv00 + (t + 1) * 32);

        // ---- QK^T : S[16 rows][32 keys] for this wave's rows
        const char* kb = (const char*)&k_lds[cur][0];
        f32x4 s0 = zf, s1 = zf;
        #pragma unroll
        for (int ks = 0; ks < 16; ++ks) {
            const int xr = (ks * 64 + g * 16) ^ ((l15 & 7) << 4);
            const s16x8 kf0 = *reinterpret_cast<const s16x8*>(kb + l15 * 1024 + xr);
            const s16x8 kf1 = *reinterpret_cast<const s16x8*>(kb + (16 + l15) * 1024 + xr);
            s0 = mfma_bf16(qf[ks], kf0, s0);
            s1 = mfma_bf16(qf[ks], kf1, s1);
        }

        // ---- P = exp2(S - FIXED_M) -> shared P LDS; per-lane l partials
        #pragma unroll
        for (int j = 0; j < 4; j++) {
            const float p0 = exp2f(s0[j] - FIXED_M);
            const float p1 = exp2f(s1[j] - FIXED_M);
            lrow[j] += p0 + p1;
            const int pr = wave * 16 + g * 4 + j;
            p_lds[pr][l15]      = tbf(p0);
            p_lds[pr][16 + l15] = tbf(p1);
        }

        // barrier(1): P complete + all QK reads of k-buf done
        asm volatile("s_waitcnt lgkmcnt(0)" ::: "memory");
        __builtin_amdgcn_sched_barrier(0);
        __builtin_amdgcn_s_barrier();
        __builtin_amdgcn_sched_barrier(0);

        // ---- PV (d-split): O[128 rows][wave's 64 cols] += P[128][32] @ V-slice
        {
            const char* vb = (const char*)&vt_lds[cur][0];
            s16x8 vf[4];
            #pragma unroll
            for (int cf = 0; cf < 4; cf++) {
                const int d = wave * 64 + cf * 16 + l15;
                vf[cf] = *reinterpret_cast<const s16x8*>(
                    vb + d * 64 + ((g * 16) ^ (((d >> 1) & 3) << 4)));
            }
            #pragma unroll
            for (int rf = 0; rf < 8; rf++) {
                const s16x8 pf = *reinterpret_cast<const s16x8*>(
                    &p_lds[rf * 16 + l15][g * 8]);
                #pragma unroll
                for (int cf = 0; cf < 4; cf++)
                    o[rf][cf] = mfma_bf16(pf, vf[cf], o[rf][cf]);
            }
        }

        // barrier(2): PV reads done (v-buf & P free); staged t+1 landed
        asm volatile("s_waitcnt vmcnt(0) lgkmcnt(0)" ::: "memory");
        __builtin_amdgcn_sched_barrier(0);
        __builtin_amdgcn_s_barrier();
        __builtin_amdgcn_sched_barrier(0);
        cur ^= 1;
    }
#undef STAGE

    // ---- l: reduce across 16 key-lanes; publish per-row
    #pragma unroll
    for (int j = 0; j < 4; j++) {
        #pragma unroll
        for (int msk = 8; msk >= 1; msk >>= 1)
            lrow[j] += __shfl_xor(lrow[j], msk, 64);
    }
    if (l15 == 0) {
        #pragma unroll
        for (int j = 0; j < 4; j++)
            l_lds[wave * 16 + g * 4 + j] = lrow[j];
    }
    __builtin_amdgcn_s_barrier();

    const int qrowb = qblk * 128;
    if (opart != nullptr) {
        const size_t prow8k = (size_t)batch * 4096;
        if (l15 == 0) {
            #pragma unroll
            for (int j = 0; j < 4; j++) {
                const size_t r = prow8k + qrowb + wave * 16 + g * 4 + j;
                ml[((size_t)split * 8192 + r) * 2 + 1] = lrow[j];
            }
        }
        ushort_t* op = opart + (size_t)split * 8192 * 512;
        #pragma unroll
        for (int rf = 0; rf < 8; rf++) {
            #pragma unroll
            for (int cf = 0; cf < 4; cf++) {
                #pragma unroll
                for (int j = 0; j < 4; j++) {
                    const size_t r = prow8k + qrowb + rf * 16 + g * 4 + j;
                    op[r * 512 + wave * 64 + cf * 16 + l15] = f2bf(o[rf][cf][j]);
                }
            }
        }
    } else {
        #pragma unroll
        for (int rf = 0; rf < 8; rf++) {
            #pragma unroll
            for (int j = 0; j < 4; j++) {
                const int rl = rf * 16 + g * 4 + j;
                const float inv = 1.0f / l_lds[rl];
                #pragma unroll
                for (int cf = 0; cf < 4; cf++) {
                    out[base + (size_t)(qrowb + rl) * 512 + wave * 64 + cf * 16 + l15]
                        = o[rf][cf][j] * inv;
                }
            }
        }
    }
}

// ---------------------------------------------------------------------------
// Kernel 3: merge KV-split partials. Fixed-M => equal weights:
// out = (sum_s O_s) / (sum_s l_s). 1 wave/row, 4 rows/block.
// ---------------------------------------------------------------------------
__global__ __launch_bounds__(256) void merge_kernel(
    const ushort_t* __restrict__ opart, const float* __restrict__ ml,
    float* __restrict__ out, int SP)
{
    const int row  = blockIdx.x * 4 + (threadIdx.x >> 6);
    const int lane = threadIdx.x & 63;

    float denom = 0.0f;
    for (int s = 0; s < SP; s++)
        denom += ml[((size_t)s * 8192 + row) * 2 + 1];
    const float inv = 1.0f / denom;

    float acc[8] = {};
    for (int s = 0; s < SP; s++) {
        const s16x8 v = *reinterpret_cast<const s16x8*>(
            opart + ((size_t)s * 8192 + row) * 512 + lane * 8);
        #pragma unroll
        for (int i = 0; i < 8; i++)
            acc[i] += bf2f((ushort_t)v[i]);
    }
    float* dst = out + (size_t)row * 512 + lane * 8;
    #pragma unroll
    for (int i = 0; i < 8; i++) dst[i] = acc[i] * inv;
}

extern "C" void kernel_launch(void* const* d_in, const int* in_sizes, int n_in,
                              void* d_out, int out_size, void* d_ws, size_t ws_size,
                              hipStream_t stream) {
    const float* x  = (const float*)d_in[0];
    const float* Wq = (const float*)d_in[1];
    const float* bq = (const float*)d_in[2];
    const float* Wk = (const float*)d_in[3];
    const float* bk = (const float*)d_in[4];
    const float* Wv = (const float*)d_in[5];
    const float* bv = (const float*)d_in[6];
    float* out = (float*)d_out;
    ushort_t* qkv = (ushort_t*)d_ws;  // q | k | vt, each 8192*512 bf16
    (void)in_sizes; (void)n_in; (void)out_size;

    const size_t qkv_bytes = 3ull * 8192 * 512 * 2;  // 25165824

    int SP = 0;
    if (ws_size >= qkv_bytes + 4ull * (8388608 + 65536)) SP = 4;
    else if (ws_size >= qkv_bytes + 2ull * (8388608 + 65536)) SP = 2;
    else if (ws_size >= qkv_bytes + 1ull * (8388608 + 65536)) SP = 1;

    dim3 gp(64, 4);
    qkv_proj_fused<<<gp, 256, 0, stream>>>(x, Wq, bq, Wk, bk, Wv, bv, qkv);

    if (SP > 0) {
        ushort_t* opart = qkv + 3ull * 8192 * 512;
        float* ml = (float*)(opart + (size_t)SP * 8192 * 512);
        dim3 ga(2 * SP, 32);
        attn_v10<<<ga, 512, 0, stream>>>(qkv, opart, ml, out, SP, (4096 / SP) / 32);
        merge_kernel<<<2048, 256, 0, stream>>>(opart, ml, out, SP);
    } else {
        dim3 ga(2, 32);
        attn_v10<<<ga, 512, 0, stream>>>(qkv, nullptr, nullptr, out, 1, 128);
    }
}